// Round 1
// baseline (324.578 us; speedup 1.0000x reference)
//
#include <hip/hip_runtime.h>
#include <stdint.h>

#define NN 8192
#define DD 1024
#define CCHUNK 8          // column chunks (split-LSE)
#define BM 128            // rows per block
#define BN 128            // cols per strip
#define BK 32             // K tile
#define L2E 1.4426950408889634f

typedef short s8v __attribute__((ext_vector_type(8)));   // 8 bf16 = 4 VGPR
typedef float f4v __attribute__((ext_vector_type(4)));   // MFMA C/D
typedef unsigned short u16;

__device__ __forceinline__ void async16(const void* g, void* l) {
  __builtin_amdgcn_global_load_lds(
      (const __attribute__((address_space(1))) void*)g,
      (__attribute__((address_space(3))) void*)l, 16, 0, 0);
}

__device__ __forceinline__ u16 f2bf(float f) {
  unsigned u = __float_as_uint(f);
  u += 0x7fffu + ((u >> 16) & 1u);   // RNE
  return (u16)(u >> 16);
}

// ---- fp32 -> bf16 conversion of both operands ----
__global__ void cvt_kernel(const float* __restrict__ r, const float* __restrict__ l,
                           u16* __restrict__ rb, u16* __restrict__ lb) {
  const float* src = blockIdx.y ? l : r;
  u16* dst = blockIdx.y ? lb : rb;
  size_t i = (size_t)blockIdx.x * blockDim.x + threadIdx.x;  // float4 index
  float4 v = ((const float4*)src)[i];
  ushort4 o;
  o.x = f2bf(v.x); o.y = f2bf(v.y); o.z = f2bf(v.z); o.w = f2bf(v.w);
  ((ushort4*)dst)[i] = o;
}

// ---- exact fp32 diagonal: sum_i <R[i], L[i]> ----
__global__ void diag_kernel(const float* __restrict__ r, const float* __restrict__ l,
                            float* __restrict__ accum) {
  int tid = threadIdx.x, lane = tid & 63, w = tid >> 6;
  int row = blockIdx.x * 4 + w;
  const float4* rp = (const float4*)(r + (size_t)row * DD);
  const float4* lp = (const float4*)(l + (size_t)row * DD);
  float s = 0.f;
#pragma unroll
  for (int j = 0; j < 4; ++j) {
    float4 a = rp[j * 64 + lane];
    float4 b = lp[j * 64 + lane];
    s += a.x * b.x + a.y * b.y + a.z * b.z + a.w * b.w;
  }
#pragma unroll
  for (int m = 1; m <= 32; m <<= 1) s += __shfl_xor(s, m);
  __shared__ float red[4];
  if (lane == 0) red[w] = s;
  __syncthreads();
  if (tid == 0) atomicAdd(accum, red[0] + red[1] + red[2] + red[3]);
}

// ---- fused bf16 GEMM + online logsumexp over one column chunk ----
__global__ __launch_bounds__(256, 2) void gemm_lse(
    const u16* __restrict__ Rb, const u16* __restrict__ Lb,
    float* __restrict__ pm, float* __restrict__ ps) {
  __shared__ u16 As[BM * BK];          // 8 KB
  __shared__ u16 Bs[BN * BK];          // 8 KB
  __shared__ float smm[2][BM], sms[2][BM];

  const int tid = threadIdx.x, lane = tid & 63, w = tid >> 6;
  const int wy = w >> 1, wx = w & 1;
  const int quad = lane >> 4, l15 = lane & 15;
  const int row0 = blockIdx.x * BM;
  const int col0 = blockIdx.y * (NN / CCHUNK);

  // staging assignments: granule g = (w*2+c)*64 + lane; row=g>>2, kq=g&3
  size_t gAo[2], gBo[2];
  u16 *lAp[2], *lBp[2];
#pragma unroll
  for (int c = 0; c < 2; ++c) {
    int g = (w * 2 + c) * 64 + lane;
    gAo[c] = (size_t)(row0 + (g >> 2)) * DD + (g & 3) * 8;
    gBo[c] = (size_t)(g >> 2) * DD + (g & 3) * 8;   // + strip col base later
    lAp[c] = As + (w * 2 + c) * 512;
    lBp[c] = Bs + (w * 2 + c) * 512;
  }

  float m_run[4][4], s_run[4][4];
#pragma unroll
  for (int i = 0; i < 4; ++i)
#pragma unroll
    for (int j = 0; j < 4; ++j) { m_run[i][j] = -__builtin_inff(); s_run[i][j] = 0.f; }

  for (int strip = 0; strip < (NN / CCHUNK) / BN; ++strip) {
    const u16* gB_base = Lb + (size_t)(col0 + strip * BN) * DD;
    f4v acc[4][4];
#pragma unroll
    for (int ri = 0; ri < 4; ++ri)
#pragma unroll
      for (int ci = 0; ci < 4; ++ci) acc[ri][ci] = (f4v){0.f, 0.f, 0.f, 0.f};

    for (int kt = 0; kt < DD / BK; ++kt) {
      const int k = kt * BK;
      async16(Rb + gAo[0] + k, lAp[0]);
      async16(Rb + gAo[1] + k, lAp[1]);
      async16(gB_base + gBo[0] + k, lBp[0]);
      async16(gB_base + gBo[1] + k, lBp[1]);
      __syncthreads();
      s8v a[4], b[4];
#pragma unroll
      for (int ri = 0; ri < 4; ++ri)
        a[ri] = *(const s8v*)(As + (wy * 64 + ri * 16 + l15) * BK + quad * 8);
#pragma unroll
      for (int ci = 0; ci < 4; ++ci)
        b[ci] = *(const s8v*)(Bs + (wx * 64 + ci * 16 + l15) * BK + quad * 8);
#pragma unroll
      for (int ri = 0; ri < 4; ++ri)
#pragma unroll
        for (int ci = 0; ci < 4; ++ci)
          acc[ri][ci] = __builtin_amdgcn_mfma_f32_16x16x32_bf16(a[ri], b[ci], acc[ri][ci], 0, 0, 0);
      __syncthreads();
    }

    // online softmax update: row = wy*64 + ri*16 + quad*4 + reg; cols = 4 ci x 16 lanes
#pragma unroll
    for (int ri = 0; ri < 4; ++ri) {
#pragma unroll
      for (int reg = 0; reg < 4; ++reg) {
        float v0 = acc[ri][0][reg], v1 = acc[ri][1][reg];
        float v2 = acc[ri][2][reg], v3 = acc[ri][3][reg];
        float t = fmaxf(fmaxf(v0, v1), fmaxf(v2, v3));
#pragma unroll
        for (int m = 1; m <= 8; m <<= 1) t = fmaxf(t, __shfl_xor(t, m));
        float mo = m_run[ri][reg];
        float mn = fmaxf(mo, t);
        float p = exp2f((v0 - mn) * L2E) + exp2f((v1 - mn) * L2E) +
                  exp2f((v2 - mn) * L2E) + exp2f((v3 - mn) * L2E);
#pragma unroll
        for (int m = 1; m <= 8; m <<= 1) p += __shfl_xor(p, m);
        s_run[ri][reg] = s_run[ri][reg] * exp2f((mo - mn) * L2E) + p;
        m_run[ri][reg] = mn;
      }
    }
  }

  // merge the two waves (wx=0/1) that share rows
  __syncthreads();
  if (l15 == 0) {
#pragma unroll
    for (int ri = 0; ri < 4; ++ri)
#pragma unroll
      for (int reg = 0; reg < 4; ++reg) {
        int r = wy * 64 + ri * 16 + quad * 4 + reg;
        smm[wx][r] = m_run[ri][reg];
        sms[wx][r] = s_run[ri][reg];
      }
  }
  __syncthreads();
  if (tid < BM) {
    float m1 = smm[0][tid], m2 = smm[1][tid];
    float M = fmaxf(m1, m2);
    float S = sms[0][tid] * exp2f((m1 - M) * L2E) + sms[1][tid] * exp2f((m2 - M) * L2E);
    pm[(size_t)(row0 + tid) * CCHUNK + blockIdx.y] = M;
    ps[(size_t)(row0 + tid) * CCHUNK + blockIdx.y] = S;
  }
}

// ---- combine chunk partials -> lse per row -> sum ----
__global__ void lse_merge(const float* __restrict__ pm, const float* __restrict__ ps,
                          float* __restrict__ accum) {
  int tid = threadIdx.x, lane = tid & 63, w = tid >> 6;
  int row = blockIdx.x * 256 + tid;
  float M = -__builtin_inff();
#pragma unroll
  for (int c = 0; c < CCHUNK; ++c) M = fmaxf(M, pm[(size_t)row * CCHUNK + c]);
  float S = 0.f;
#pragma unroll
  for (int c = 0; c < CCHUNK; ++c)
    S += ps[(size_t)row * CCHUNK + c] * exp2f((pm[(size_t)row * CCHUNK + c] - M) * L2E);
  float lse = M + logf(S);
#pragma unroll
  for (int m = 1; m <= 32; m <<= 1) lse += __shfl_xor(lse, m);
  __shared__ float red[4];
  if (lane == 0) red[w] = lse;
  __syncthreads();
  if (tid == 0) atomicAdd(accum, red[0] + red[1] + red[2] + red[3]);
}

__global__ void finalize(const float* __restrict__ accum, float* __restrict__ out) {
  // accum[0] = sum(diag), accum[1] = sum(lse)
  out[0] = (accum[1] - accum[0]) * (1.0f / (float)NN);
}

extern "C" void kernel_launch(void* const* d_in, const int* in_sizes, int n_in,
                              void* d_out, int out_size, void* d_ws, size_t ws_size,
                              hipStream_t stream) {
  const float* r = (const float*)d_in[0];
  const float* l = (const float*)d_in[1];
  float* out = (float*)d_out;
  char* ws = (char*)d_ws;

  float* accum = (float*)ws;                                   // [0]=diag,[1]=lse
  u16* Rb = (u16*)(ws + 256);
  u16* Lb = (u16*)(ws + 256 + (size_t)NN * DD * 2);
  float* pm = (float*)(ws + 256 + (size_t)NN * DD * 4);
  float* ps = pm + (size_t)NN * CCHUNK;

  hipMemsetAsync(accum, 0, 8, stream);
  cvt_kernel<<<dim3(NN * DD / 4 / 256, 2), 256, 0, stream>>>(r, l, Rb, Lb);
  diag_kernel<<<NN / 4, 256, 0, stream>>>(r, l, accum);
  gemm_lse<<<dim3(NN / BM, CCHUNK), 256, 0, stream>>>(Rb, Lb, pm, ps);
  lse_merge<<<NN / 256, 256, 0, stream>>>(pm, ps, accum + 1);
  finalize<<<1, 1, 0, stream>>>(accum, out);
}